// Round 9
// baseline (811.530 us; speedup 1.0000x reference)
//
#include <hip/hip_runtime.h>
#include <hip/hip_bf16.h>
#include <hip/hip_cooperative_groups.h>

namespace cg = cooperative_groups;

#define NIN 1024
#define NL 128
#define MS 16384    // 128x128 matrix slot (elements)
#define CMS 32768   // 256x128 C slot (elements)

typedef __attribute__((ext_vector_type(8))) short bf16x8_t;
typedef __attribute__((ext_vector_type(4))) float f32x4_t;

__device__ inline unsigned short f2bf(float f) {
    __hip_bfloat16 h = __float2bfloat16(f);
    return *reinterpret_cast<unsigned short*>(&h);
}

// f32 tile: D[r0..r0+32)[j0..j0+64) = A_rows @ B(128x128); optional bf16 copy.
// Uses 50 KB of lds.
__device__ __forceinline__ void pmm32x64(const float* __restrict__ A,
                                         const float* __restrict__ B,
                                         float* __restrict__ D,
                                         unsigned short* __restrict__ Db,
                                         int r0, int j0, char* lds) {
    float* Bl = (float*)lds;                        // [128][64] 32 KB
    float (*At)[36] = (float(*)[36])(lds + 32768);  // [128][36] 18 KB
    int t = threadIdx.x;
    for (int idx = t; idx < 2048; idx += 256) {
        int row = idx >> 4, c = idx & 15;
        *(float4*)&Bl[row * 64 + c * 4] = *(const float4*)&B[row * NL + j0 + c * 4];
    }
    for (int idx = t; idx < 4096; idx += 256) {
        int m = idx >> 7, kk = idx & 127;
        At[kk][m] = A[(size_t)(r0 + m) * NL + kk];
    }
    __syncthreads();
    int j = t & 63, rg = t >> 6;
    float acc[8];
#pragma unroll
    for (int q = 0; q < 8; ++q) acc[q] = 0.f;
#pragma unroll 4
    for (int kk = 0; kk < NL; ++kk) {
        float bv = Bl[kk * 64 + j];
        const f32x4_t* ap = (const f32x4_t*)&At[kk][rg * 8];
        f32x4_t a0 = ap[0], a1 = ap[1];
        acc[0] += a0[0] * bv; acc[1] += a0[1] * bv;
        acc[2] += a0[2] * bv; acc[3] += a0[3] * bv;
        acc[4] += a1[0] * bv; acc[5] += a1[1] * bv;
        acc[6] += a1[2] * bv; acc[7] += a1[3] * bv;
    }
#pragma unroll
    for (int q = 0; q < 8; ++q) {
        size_t off = (size_t)(r0 + rg * 8 + q) * NL + j0 + j;
        D[off] = acc[q];
        if (Db) Db[off] = f2bf(acc[q]);
    }
}

// H tile (bf16 MFMA, swapped operands): H[(n*16+a)][m] = sum_l F[n,l]*T^{a+1}[m,l]
// Stages only the T-tile (32 KB); F fragments read direct from L2-resident Fb.
__device__ __forceinline__ void hmfma(const unsigned short* __restrict__ Fb,
                                      const unsigned short* __restrict__ Wa,
                                      unsigned short* __restrict__ H,
                                      int a, int nt, char* lds) {
    char* lB = lds;  // swizzled T tile, 32 KB
    int t = threadIdx.x;
    for (int i = t; i < 2048; i += 256) {
        int row = i >> 4, c = i & 15;
        int sw = (c * 16) ^ ((row & 7) << 4);
        *(bf16x8_t*)(lB + row * 256 + sw) = *(const bf16x8_t*)(Wa + (size_t)row * NL + c * 8);
    }
    __syncthreads();
    int w = t >> 6, lane = t & 63;
    int wn = (w >> 1) * 64, wm = (w & 1) * 64;
    int r = lane & 15, g = lane >> 4;
    const unsigned short* Ag = Fb + (size_t)(nt * 128) * NL;
    bf16x8_t av[4][4];  // [kk][aa]
#pragma unroll
    for (int kk = 0; kk < 4; ++kk) {
        int c16 = kk * 4 + g;
#pragma unroll
        for (int aa = 0; aa < 4; ++aa)
            av[kk][aa] = *(const bf16x8_t*)(Ag + (size_t)(wn + aa * 16 + r) * NL + c16 * 8);
    }
    f32x4_t acc[4][4];
#pragma unroll
    for (int aa = 0; aa < 4; ++aa)
#pragma unroll
        for (int bb = 0; bb < 4; ++bb) acc[aa][bb] = (f32x4_t){0.f, 0.f, 0.f, 0.f};
#pragma unroll
    for (int kk = 0; kk < 4; ++kk) {
        int c16 = kk * 4 + g;
        bf16x8_t bv[4];
#pragma unroll
        for (int bb = 0; bb < 4; ++bb) {
            int rowB = wm + bb * 16 + r;
            bv[bb] = *(const bf16x8_t*)(lB + rowB * 256 + ((c16 * 16) ^ ((rowB & 7) << 4)));
        }
#pragma unroll
        for (int aa = 0; aa < 4; ++aa)
#pragma unroll
            for (int bb = 0; bb < 4; ++bb)
                acc[aa][bb] = __builtin_amdgcn_mfma_f32_16x16x32_bf16(bv[bb], av[kk][aa], acc[aa][bb], 0, 0, 0);
    }
#pragma unroll
    for (int aa = 0; aa < 4; ++aa) {
        int n = nt * 128 + wn + aa * 16 + r;
#pragma unroll
        for (int bb = 0; bb < 4; ++bb) {
            int m0 = wm + bb * 16 + g * 4;
            ushort4 o;
            o.x = f2bf(acc[aa][bb][0]); o.y = f2bf(acc[aa][bb][1]);
            o.z = f2bf(acc[aa][bb][2]); o.w = f2bf(acc[aa][bb][3]);
            *(ushort4*)&H[((size_t)n * 16 + a) * NL + m0] = o;
        }
    }
}

// One phase of the preamble. All blocks of a block take the same branch.
__device__ __forceinline__ void do_phase(int ph, int blk,
                                         const float* __restrict__ x,
                                         const float* __restrict__ tf,
                                         const float* __restrict__ tr,
                                         float* __restrict__ W,
                                         unsigned short* __restrict__ Wb,
                                         unsigned short* __restrict__ Fb,
                                         float* __restrict__ Cf,
                                         unsigned short* __restrict__ Cc,
                                         unsigned short* __restrict__ H,
                                         char* lds) {
    int t = threadIdx.x;
    if (ph == 0) {
        if (blk < 128) {
            float* xr = (float*)lds;  // [2][1024] f32 = 8 KB
            int b0 = blk * 2;
            for (int idx = t; idx < 512; idx += 256) {
                int rr = idx >> 8, c = idx & 255;
                ((float4*)xr)[rr * 256 + c] =
                    ((const float4*)(x + (size_t)(b0 + rr) * NIN))[c];
            }
            __syncthreads();
            int rr = t >> 7, col = t & 127;
            const float* xp = xr + rr * NIN;
            float a = 0.f;
#pragma unroll 8
            for (int i = 0; i < NIN; ++i) a += xp[i] * tf[i * NL + col];
            Cf[(size_t)(b0 + rr) * NL + col] = a;
            Cc[(size_t)(b0 + rr) * NL + col] = f2bf(a);
        } else if (blk < 192) {
            int id = (blk - 128) * 256 + t;  // 0..16383
            float v = tr[id];
            W[id] = v;
            Wb[id] = f2bf(v);
            for (int i = id; i < NIN * NL; i += 16384) Fb[i] = f2bf(tf[i]);
        }
    } else if (ph <= 4) {
        int m = 1 << (ph - 1);
        if (blk < m * 8) {
            int i = blk >> 3, tt = blk & 7;
            pmm32x64(W + (size_t)i * MS, W + (size_t)(m - 1) * MS,
                     W + (size_t)(m + i) * MS, Wb + (size_t)(m + i) * MS,
                     ((tt >> 1) & 3) * 32, (tt & 1) * 64, lds);
        }
    } else {
        int lv = ph - 5;    // 0..3
        int b2s = 15 + lv;  // W slot of T^{16<<lv}
        int ncp = 1 << lv;
        if (lv < 3 && blk < 8) {
            // T^{32<<lv} = (T^{16<<lv})^2 -> slot 16+lv
            pmm32x64(W + (size_t)b2s * MS, W + (size_t)b2s * MS,
                     W + (size_t)(16 + lv) * MS, nullptr,
                     ((blk >> 1) & 3) * 32, (blk & 1) * 64, lds);
        } else if (blk >= 8 && blk < 8 + ncp * 16) {
            // C_{ncp+q} = C_q @ T^{16*ncp}
            int rel = blk - 8, q = rel >> 4, tt = rel & 15;
            pmm32x64(Cf + (size_t)q * CMS, W + (size_t)b2s * MS,
                     Cf + (size_t)(ncp + q) * CMS, Cc + (size_t)(ncp + q) * CMS,
                     (tt >> 1) * 32, (tt & 1) * 64, lds);
        } else if (lv == 0 && blk >= 24 && blk < 152) {
            // all H tiles at once (needs only T^1..T^16, ready after ph=4)
            int rel = blk - 24;
            hmfma(Fb, Wb + (size_t)(rel >> 3) * MS, H, rel >> 3, rel & 7, lds);
        }
    }
}

// ---------------- cooperative preamble: 9 phases, one launch ----------------
__global__ __launch_bounds__(256) void k_pre(const float* __restrict__ x,
                                             const float* __restrict__ tf,
                                             const float* __restrict__ tr,
                                             float* __restrict__ W,
                                             unsigned short* __restrict__ Wb,
                                             unsigned short* __restrict__ Fb,
                                             float* __restrict__ Cf,
                                             unsigned short* __restrict__ Cc,
                                             unsigned short* __restrict__ H) {
    cg::grid_group grid = cg::this_grid();
    __shared__ __align__(16) char lds[51200];
    for (int ph = 0; ph < 9; ++ph) {
        do_phase(ph, blockIdx.x, x, tf, tr, W, Wb, Fb, Cf, Cc, H, lds);
        __threadfence();
        grid.sync();
    }
}

// ---------------- fallback: one phase per launch ----------------------------
__global__ __launch_bounds__(256) void k_phase(int ph,
                                               const float* __restrict__ x,
                                               const float* __restrict__ tf,
                                               const float* __restrict__ tr,
                                               float* __restrict__ W,
                                               unsigned short* __restrict__ Wb,
                                               unsigned short* __restrict__ Fb,
                                               float* __restrict__ Cf,
                                               unsigned short* __restrict__ Cc,
                                               unsigned short* __restrict__ H) {
    __shared__ __align__(16) char lds[51200];
    do_phase(ph, blockIdx.x, x, tf, tr, W, Wb, Fb, Cf, Cc, H, lds);
}

// ---------------- k_main: out = Cc_j @ H^T, NT stores ----------------------
// e = ct(128)*32 + j(16)*2 + bt(2); XCD-chunked so one ct's 32 blocks share
// an XCD (their 64B chunks merge into full lines in that L2).
__global__ __launch_bounds__(256) void k_main(const unsigned short* __restrict__ Cc,
                                              const unsigned short* __restrict__ H,
                                              float* __restrict__ out) {
    int bid = blockIdx.x;
    int e = ((bid & 7) << 9) | (bid >> 3);
    int ct = e >> 5, j = (e >> 1) & 15, bt = e & 1;
    __shared__ __align__(16) char lB[128 * 256];   // swizzled H tile (32 KB)
    int t = threadIdx.x;
    const unsigned short* Bg = H + (size_t)(ct * 128) * NL;
    for (int i = t; i < 2048; i += 256) {
        int row = i >> 4, c = i & 15;
        int sw = (c * 16) ^ ((row & 7) << 4);
        *(bf16x8_t*)(lB + row * 256 + sw) =
            *(const bf16x8_t*)(Bg + (size_t)row * NL + c * 8);
    }
    __syncthreads();
    int w = t >> 6, lane = t & 63;
    int wr = (w >> 1) * 64;   // wave b-row offset
    int wc = (w & 1) * 64;    // wave col offset
    int r = lane & 15, g = lane >> 4;

    const unsigned short* Arow = Cc + (size_t)j * CMS + (size_t)(bt * 128) * NL;
    bf16x8_t av[4][4];  // [kk][mf]
#pragma unroll
    for (int kk = 0; kk < 4; ++kk) {
        int c16 = kk * 4 + g;
#pragma unroll
        for (int mf = 0; mf < 4; ++mf)
            av[kk][mf] = *(const bf16x8_t*)(Arow + (size_t)(wr + mf * 16 + r) * NL + c16 * 8);
    }
    f32x4_t acc[4][4];  // swapped -> reg dim = col, lane&15 = b-row
#pragma unroll
    for (int mf = 0; mf < 4; ++mf)
#pragma unroll
        for (int nf = 0; nf < 4; ++nf) acc[mf][nf] = (f32x4_t){0.f, 0.f, 0.f, 0.f};
#pragma unroll
    for (int kk = 0; kk < 4; ++kk) {
        int c16 = kk * 4 + g;
        bf16x8_t bv[4];
#pragma unroll
        for (int nf = 0; nf < 4; ++nf) {
            int rowB = wc + nf * 16 + r;
            bv[nf] = *(const bf16x8_t*)(lB + rowB * 256 + ((c16 * 16) ^ ((rowB & 7) << 4)));
        }
#pragma unroll
        for (int mf = 0; mf < 4; ++mf)
#pragma unroll
            for (int nf = 0; nf < 4; ++nf)
                acc[mf][nf] = __builtin_amdgcn_mfma_f32_16x16x32_bf16(bv[nf], av[kk][mf], acc[mf][nf], 0, 0, 0);
    }
#pragma unroll
    for (int mf = 0; mf < 4; ++mf) {
        int brow = bt * 128 + wr + mf * 16 + r;
#pragma unroll
        for (int nf = 0; nf < 4; ++nf) {
            int nn = (w & 1) * 4 + nf;
            __builtin_nontemporal_store(
                acc[mf][nf],
                (f32x4_t*)&out[(size_t)brow * (NIN * 256) +
                               (size_t)(ct * 8 + nn) * 256 + 16 * j + g * 4]);
        }
    }
}

extern "C" void kernel_launch(void* const* d_in, const int* in_sizes, int n_in,
                              void* d_out, int out_size, void* d_ws, size_t ws_size,
                              hipStream_t stream) {
    const float* x = (const float*)d_in[0];
    const float* tf = (const float*)d_in[1];
    const float* tr = (const float*)d_in[2];
    float* out = (float*)d_out;

    // workspace (~9 MB)
    float* W = (float*)d_ws;                              // 20 f32 slots
    float* Cf = W + (size_t)20 * MS;                      // 16 x [256][128] f32
    unsigned short* Wb = (unsigned short*)(Cf + (size_t)16 * CMS);  // 16 bf16 slots
    unsigned short* Fb = Wb + (size_t)16 * MS;            // [1024][128] bf16
    unsigned short* Cc = Fb + (size_t)NIN * NL;           // 16 x [256][128] bf16
    unsigned short* H = Cc + (size_t)16 * CMS;            // [16384][128] bf16 (4 MB)

    void* args[] = {(void*)&x, (void*)&tf, (void*)&tr, (void*)&W, (void*)&Wb,
                    (void*)&Fb, (void*)&Cf, (void*)&Cc, (void*)&H};
    hipError_t ce = hipLaunchCooperativeKernel((const void*)k_pre, dim3(256),
                                               dim3(256), args, 0, stream);
    if (ce != hipSuccess) {
        (void)hipGetLastError();  // clear sticky error
        static const int grids[9] = {192, 8, 16, 32, 64, 152, 40, 72, 136};
        for (int ph = 0; ph < 9; ++ph) {
            k_phase<<<grids[ph], 256, 0, stream>>>(ph, x, tf, tr, W, Wb, Fb,
                                                   Cf, Cc, H);
        }
    }
    k_main<<<4096, 256, 0, stream>>>(Cc, H, out);
}

// Round 10
// 182.361 us; speedup vs baseline: 4.4501x; 4.4501x over previous
//
#include <hip/hip_runtime.h>
#include <hip/hip_bf16.h>

#define NIN 1024
#define NL 128
#define MS 16384    // 128x128 matrix slot (elements)
#define CMS 32768   // 256x128 C slot (elements)

typedef __attribute__((ext_vector_type(8))) short bf16x8_t;
typedef __attribute__((ext_vector_type(4))) float f32x4_t;

__device__ inline unsigned short f2bf(float f) {
    __hip_bfloat16 h = __float2bfloat16(f);
    return *reinterpret_cast<unsigned short*>(&h);
}

// f32 tile: D[r0..r0+32)[j0..j0+64) = A_rows @ B(128x128); optional bf16 copy.
__device__ __forceinline__ void pmm32x64(const float* __restrict__ A,
                                         const float* __restrict__ B,
                                         float* __restrict__ D,
                                         unsigned short* __restrict__ Db,
                                         int r0, int j0, char* lds) {
    float* Bl = (float*)lds;                        // [128][64] 32 KB
    float (*At)[36] = (float(*)[36])(lds + 32768);  // [128][36] 18 KB
    int t = threadIdx.x;
    for (int idx = t; idx < 2048; idx += 256) {
        int row = idx >> 4, c = idx & 15;
        *(float4*)&Bl[row * 64 + c * 4] = *(const float4*)&B[row * NL + j0 + c * 4];
    }
    for (int idx = t; idx < 4096; idx += 256) {
        int m = idx >> 7, kk = idx & 127;
        At[kk][m] = A[(size_t)(r0 + m) * NL + kk];
    }
    __syncthreads();
    int j = t & 63, rg = t >> 6;
    float acc[8];
#pragma unroll
    for (int q = 0; q < 8; ++q) acc[q] = 0.f;
#pragma unroll 4
    for (int kk = 0; kk < NL; ++kk) {
        float bv = Bl[kk * 64 + j];
        const f32x4_t* ap = (const f32x4_t*)&At[kk][rg * 8];
        f32x4_t a0 = ap[0], a1 = ap[1];
        acc[0] += a0[0] * bv; acc[1] += a0[1] * bv;
        acc[2] += a0[2] * bv; acc[3] += a0[3] * bv;
        acc[4] += a1[0] * bv; acc[5] += a1[1] * bv;
        acc[6] += a1[2] * bv; acc[7] += a1[3] * bv;
    }
#pragma unroll
    for (int q = 0; q < 8; ++q) {
        size_t off = (size_t)(r0 + rg * 8 + q) * NL + j0 + j;
        D[off] = acc[q];
        if (Db) Db[off] = f2bf(acc[q]);
    }
}

// H tile (bf16 MFMA, swapped operands): H[(n*16+a)][m] = sum_l F[n,l]*T^{a+1}[m,l]
__device__ __forceinline__ void hmfma(const unsigned short* __restrict__ Fb,
                                      const unsigned short* __restrict__ Wa,
                                      unsigned short* __restrict__ H,
                                      int a, int nt, char* lds) {
    char* lB = lds;  // swizzled T tile, 32 KB
    int t = threadIdx.x;
    for (int i = t; i < 2048; i += 256) {
        int row = i >> 4, c = i & 15;
        int sw = (c * 16) ^ ((row & 7) << 4);
        *(bf16x8_t*)(lB + row * 256 + sw) = *(const bf16x8_t*)(Wa + (size_t)row * NL + c * 8);
    }
    __syncthreads();
    int w = t >> 6, lane = t & 63;
    int wn = (w >> 1) * 64, wm = (w & 1) * 64;
    int r = lane & 15, g = lane >> 4;
    const unsigned short* Ag = Fb + (size_t)(nt * 128) * NL;
    bf16x8_t av[4][4];  // [kk][aa]
#pragma unroll
    for (int kk = 0; kk < 4; ++kk) {
        int c16 = kk * 4 + g;
#pragma unroll
        for (int aa = 0; aa < 4; ++aa)
            av[kk][aa] = *(const bf16x8_t*)(Ag + (size_t)(wn + aa * 16 + r) * NL + c16 * 8);
    }
    f32x4_t acc[4][4];
#pragma unroll
    for (int aa = 0; aa < 4; ++aa)
#pragma unroll
        for (int bb = 0; bb < 4; ++bb) acc[aa][bb] = (f32x4_t){0.f, 0.f, 0.f, 0.f};
#pragma unroll
    for (int kk = 0; kk < 4; ++kk) {
        int c16 = kk * 4 + g;
        bf16x8_t bv[4];
#pragma unroll
        for (int bb = 0; bb < 4; ++bb) {
            int rowB = wm + bb * 16 + r;
            bv[bb] = *(const bf16x8_t*)(lB + rowB * 256 + ((c16 * 16) ^ ((rowB & 7) << 4)));
        }
#pragma unroll
        for (int aa = 0; aa < 4; ++aa)
#pragma unroll
            for (int bb = 0; bb < 4; ++bb)
                acc[aa][bb] = __builtin_amdgcn_mfma_f32_16x16x32_bf16(bv[bb], av[kk][aa], acc[aa][bb], 0, 0, 0);
    }
#pragma unroll
    for (int aa = 0; aa < 4; ++aa) {
        int n = nt * 128 + wn + aa * 16 + r;
#pragma unroll
        for (int bb = 0; bb < 4; ++bb) {
            int m0 = wm + bb * 16 + g * 4;
            ushort4 o;
            o.x = f2bf(acc[aa][bb][0]); o.y = f2bf(acc[aa][bb][1]);
            o.z = f2bf(acc[aa][bb][2]); o.w = f2bf(acc[aa][bb][3]);
            *(ushort4*)&H[((size_t)n * 16 + a) * NL + m0] = o;
        }
    }
}

// ---------------- one preamble phase per launch -----------------------------
// ph0 (200 blk): lat0; tr->W0/Wb0, tf->Fb; T^2 = tr@tr -> W1/Wb1
// ph1..3: T-chain to T^16 (W slots power-1)
// ph4 (152): T^32 square | C1=C0@T^16 | all 128 H tiles
// ph5 (40):  T^64 square | C2,3 = C0,1 @ T^32
// ph6 (72):  T^128 square | C4..7 = C0..3 @ T^64
// ph7 (136): C8..15 = C0..7 @ T^128   (blocks 0..7 idle)
__global__ __launch_bounds__(256) void k_phase(int ph,
                                               const float* __restrict__ x,
                                               const float* __restrict__ tf,
                                               const float* __restrict__ tr,
                                               float* __restrict__ W,
                                               unsigned short* __restrict__ Wb,
                                               unsigned short* __restrict__ Fb,
                                               float* __restrict__ Cf,
                                               unsigned short* __restrict__ Cc,
                                               unsigned short* __restrict__ H) {
    __shared__ __align__(16) char lds[51200];
    int blk = blockIdx.x, t = threadIdx.x;
    if (ph == 0) {
        if (blk < 128) {
            float* xr = (float*)lds;  // [2][1024]
            int b0 = blk * 2;
            for (int idx = t; idx < 512; idx += 256) {
                int rr = idx >> 8, c = idx & 255;
                ((float4*)xr)[rr * 256 + c] =
                    ((const float4*)(x + (size_t)(b0 + rr) * NIN))[c];
            }
            __syncthreads();
            int rr = t >> 7, col = t & 127;
            const float* xp = xr + rr * NIN;
            float a = 0.f;
#pragma unroll 8
            for (int i = 0; i < NIN; ++i) a += xp[i] * tf[i * NL + col];
            Cf[(size_t)(b0 + rr) * NL + col] = a;
            Cc[(size_t)(b0 + rr) * NL + col] = f2bf(a);
        } else if (blk < 192) {
            int id = (blk - 128) * 256 + t;  // 0..16383
            float v = tr[id];
            W[id] = v;
            Wb[id] = f2bf(v);
            for (int i = id; i < NIN * NL; i += 16384) Fb[i] = f2bf(tf[i]);
        } else {
            int tt = blk - 192;  // 0..7: T^2 = tr @ tr -> slot 1
            pmm32x64(tr, tr, W + MS, Wb + MS,
                     ((tt >> 1) & 3) * 32, (tt & 1) * 64, lds);
        }
    } else if (ph <= 3) {
        int m = 2 << (ph - 1);  // 2,4,8
        // T^{m+1..2m} = T^{1..m} @ T^m
        int i = blk >> 3, tt = blk & 7;
        pmm32x64(W + (size_t)i * MS, W + (size_t)(m - 1) * MS,
                 W + (size_t)(m + i) * MS, Wb + (size_t)(m + i) * MS,
                 ((tt >> 1) & 3) * 32, (tt & 1) * 64, lds);
    } else {
        int lv = ph - 4;    // 0..3
        int b2s = 15 + lv;  // W slot of T^{16<<lv}
        int ncp = 1 << lv;
        if (lv < 3 && blk < 8) {
            pmm32x64(W + (size_t)b2s * MS, W + (size_t)b2s * MS,
                     W + (size_t)(16 + lv) * MS, nullptr,
                     ((blk >> 1) & 3) * 32, (blk & 1) * 64, lds);
        } else if (blk >= 8 && blk < 8 + ncp * 16) {
            int rel = blk - 8, q = rel >> 4, tt = rel & 15;
            pmm32x64(Cf + (size_t)q * CMS, W + (size_t)b2s * MS,
                     Cf + (size_t)(ncp + q) * CMS, Cc + (size_t)(ncp + q) * CMS,
                     (tt >> 1) * 32, (tt & 1) * 64, lds);
        } else if (lv == 0 && blk >= 24 && blk < 152) {
            int rel = blk - 24;
            hmfma(Fb, Wb + (size_t)(rel >> 3) * MS, H, rel >> 3, rel & 7, lds);
        }
    }
}

// ---------------- k_main: out = Cc_j @ H^T, NT stores ----------------------
// e = ct(128)*32 + j(16)*2 + bt(2); XCD-chunked so one ct's 32 blocks share
// an XCD (their 64B chunks merge into full lines in that L2).
__global__ __launch_bounds__(256) void k_main(const unsigned short* __restrict__ Cc,
                                              const unsigned short* __restrict__ H,
                                              float* __restrict__ out) {
    int bid = blockIdx.x;
    int e = ((bid & 7) << 9) | (bid >> 3);
    int ct = e >> 5, j = (e >> 1) & 15, bt = e & 1;
    __shared__ __align__(16) char lB[128 * 256];   // swizzled H tile (32 KB)
    int t = threadIdx.x;
    const unsigned short* Bg = H + (size_t)(ct * 128) * NL;
    for (int i = t; i < 2048; i += 256) {
        int row = i >> 4, c = i & 15;
        int sw = (c * 16) ^ ((row & 7) << 4);
        *(bf16x8_t*)(lB + row * 256 + sw) =
            *(const bf16x8_t*)(Bg + (size_t)row * NL + c * 8);
    }
    __syncthreads();
    int w = t >> 6, lane = t & 63;
    int wr = (w >> 1) * 64;   // wave b-row offset
    int wc = (w & 1) * 64;    // wave col offset
    int r = lane & 15, g = lane >> 4;

    const unsigned short* Arow = Cc + (size_t)j * CMS + (size_t)(bt * 128) * NL;
    bf16x8_t av[4][4];  // [kk][mf]
#pragma unroll
    for (int kk = 0; kk < 4; ++kk) {
        int c16 = kk * 4 + g;
#pragma unroll
        for (int mf = 0; mf < 4; ++mf)
            av[kk][mf] = *(const bf16x8_t*)(Arow + (size_t)(wr + mf * 16 + r) * NL + c16 * 8);
    }
    f32x4_t acc[4][4];  // swapped -> reg dim = col, lane&15 = b-row
#pragma unroll
    for (int mf = 0; mf < 4; ++mf)
#pragma unroll
        for (int nf = 0; nf < 4; ++nf) acc[mf][nf] = (f32x4_t){0.f, 0.f, 0.f, 0.f};
#pragma unroll
    for (int kk = 0; kk < 4; ++kk) {
        int c16 = kk * 4 + g;
        bf16x8_t bv[4];
#pragma unroll
        for (int nf = 0; nf < 4; ++nf) {
            int rowB = wc + nf * 16 + r;
            bv[nf] = *(const bf16x8_t*)(lB + rowB * 256 + ((c16 * 16) ^ ((rowB & 7) << 4)));
        }
#pragma unroll
        for (int mf = 0; mf < 4; ++mf)
#pragma unroll
            for (int nf = 0; nf < 4; ++nf)
                acc[mf][nf] = __builtin_amdgcn_mfma_f32_16x16x32_bf16(bv[nf], av[kk][mf], acc[mf][nf], 0, 0, 0);
    }
#pragma unroll
    for (int mf = 0; mf < 4; ++mf) {
        int brow = bt * 128 + wr + mf * 16 + r;
#pragma unroll
        for (int nf = 0; nf < 4; ++nf) {
            int nn = (w & 1) * 4 + nf;
            __builtin_nontemporal_store(
                acc[mf][nf],
                (f32x4_t*)&out[(size_t)brow * (NIN * 256) +
                               (size_t)(ct * 8 + nn) * 256 + 16 * j + g * 4]);
        }
    }
}

extern "C" void kernel_launch(void* const* d_in, const int* in_sizes, int n_in,
                              void* d_out, int out_size, void* d_ws, size_t ws_size,
                              hipStream_t stream) {
    const float* x = (const float*)d_in[0];
    const float* tf = (const float*)d_in[1];
    const float* tr = (const float*)d_in[2];
    float* out = (float*)d_out;

    // workspace (~9 MB)
    float* W = (float*)d_ws;                              // 20 f32 slots
    float* Cf = W + (size_t)20 * MS;                      // 16 x [256][128] f32
    unsigned short* Wb = (unsigned short*)(Cf + (size_t)16 * CMS);  // 16 bf16 slots
    unsigned short* Fb = Wb + (size_t)16 * MS;            // [1024][128] bf16
    unsigned short* Cc = Fb + (size_t)NIN * NL;           // 16 x [256][128] bf16
    unsigned short* H = Cc + (size_t)16 * CMS;            // [16384][128] bf16 (4 MB)

    static const int grids[8] = {200, 16, 32, 64, 152, 40, 72, 136};
    for (int ph = 0; ph < 8; ++ph) {
        k_phase<<<grids[ph], 256, 0, stream>>>(ph, x, tf, tr, W, Wb, Fb,
                                               Cf, Cc, H);
    }
    k_main<<<4096, 256, 0, stream>>>(Cc, H, out);
}